// Round 2
// baseline (1488.968 us; speedup 1.0000x reference)
//
#include <hip/hip_runtime.h>
#include <hip/hip_bf16.h>
#include <cstddef>

// Problem constants
#define LYR 2
#define NH 8
#define HID 512
#define SEQ 1024
#define BATCH 4
#define WBAND 34   // W+1 = 34 valid relative offsets
#define MROWS (BATCH*SEQ)   // 4096

#define BM 64
#define BN 64
#define BK 16

// C[M,N] = A[M,K] @ W[N,K]^T + bias[N], C has leading dim ldc.
__global__ __launch_bounds__(256)
void gemm_bt(const float* __restrict__ A, const float* __restrict__ W,
             const float* __restrict__ bias, float* __restrict__ C,
             int M, int N, int K, int ldc) {
  __shared__ __align__(16) float As[BK][BM + 4];
  __shared__ __align__(16) float Bs[BK][BN + 4];
  const int tid = threadIdx.x;
  const int tx = tid & 15;        // N dir (0..15)
  const int ty = tid >> 4;        // M dir (0..15)
  const int lr = tid >> 2;        // load row 0..63
  const int lk = (tid & 3) << 2;  // load k offset 0,4,8,12
  const int bx = blockIdx.x, by = blockIdx.y;

  const float* Ap = A + (size_t)(by * BM + lr) * K + lk;
  const float* Wp = W + (size_t)(bx * BN + lr) * K + lk;

  float acc[4][4] = {};
  for (int k0 = 0; k0 < K; k0 += BK) {
    float4 a4 = *(const float4*)(Ap + k0);
    float4 b4 = *(const float4*)(Wp + k0);
    __syncthreads();
    As[lk + 0][lr] = a4.x; As[lk + 1][lr] = a4.y;
    As[lk + 2][lr] = a4.z; As[lk + 3][lr] = a4.w;
    Bs[lk + 0][lr] = b4.x; Bs[lk + 1][lr] = b4.y;
    Bs[lk + 2][lr] = b4.z; Bs[lk + 3][lr] = b4.w;
    __syncthreads();
#pragma unroll
    for (int kk = 0; kk < BK; ++kk) {
      float4 av = *(const float4*)(&As[kk][ty << 2]);
      float4 bv = *(const float4*)(&Bs[kk][tx << 2]);
      float a[4] = {av.x, av.y, av.z, av.w};
      float b[4] = {bv.x, bv.y, bv.z, bv.w};
#pragma unroll
      for (int i = 0; i < 4; ++i)
#pragma unroll
        for (int j = 0; j < 4; ++j)
          acc[i][j] = fmaf(a[i], b[j], acc[i][j]);
    }
  }
  const int cm = by * BM + (ty << 2);
  const int cn = bx * BN + (tx << 2);
  float4 bb = *(const float4*)(bias + cn);
#pragma unroll
  for (int i = 0; i < 4; ++i) {
    float4 o;
    o.x = acc[i][0] + bb.x; o.y = acc[i][1] + bb.y;
    o.z = acc[i][2] + bb.z; o.w = acc[i][3] + bb.w;
    *(float4*)(C + (size_t)(cm + i) * ldc + cn) = o;
  }
}

// Banded attention. QKV: [B*S, 1536] rows = [q(512)|k(512)|v(512)].
// One wave per (b,h,i). O: [B*S, 512].
__global__ __launch_bounds__(256)
void band_attn(const float* __restrict__ QKV, const float* __restrict__ rel,
               float* __restrict__ O, int left) {
  const int LDQ = 3 * HID;
  const int wave = threadIdx.x >> 6;
  const int lane = threadIdx.x & 63;
  const int i = (blockIdx.x << 2) + wave;
  const int h = blockIdx.y;
  const int b = blockIdx.z;
  const size_t rowbase = (size_t)b * SEQ * LDQ + h * 64;
  const float* Qr = QKV + rowbase + (size_t)i * LDQ;

  // Phase 1: lane t<34 computes score_t = q.k_j/8 + rel[h][t]
  float score = -1e30f;
  {
    const int t = lane;
    const int j = left ? (i - 33 + t) : (i + t);
    if (t < WBAND && j >= 0 && j < SEQ) {
      const float4* q4 = (const float4*)Qr;
      const float4* k4 = (const float4*)(QKV + rowbase + 512 + (size_t)j * LDQ);
      float s = 0.f;
#pragma unroll
      for (int dd = 0; dd < 16; ++dd) {
        float4 q = q4[dd], k = k4[dd];
        s = fmaf(q.x, k.x, fmaf(q.y, k.y, fmaf(q.z, k.z, fmaf(q.w, k.w, s))));
      }
      score = s * 0.125f + rel[h * WBAND + t];
    }
  }
  // Phase 2: softmax across the 64 lanes (invalid lanes at -1e30 -> p=0)
  float m = score;
#pragma unroll
  for (int off = 32; off; off >>= 1) m = fmaxf(m, __shfl_xor(m, off));
  float p = __expf(score - m);
  float sum = p;
#pragma unroll
  for (int off = 32; off; off >>= 1) sum += __shfl_xor(sum, off);
  p /= sum;
  // Phase 3: out[d] = sum_t p_t * V[j_t][d]  (lane = d, coalesced V reads)
  float o = 0.f;
  const int d = lane;
  const float* Vb = QKV + rowbase + 1024 + d;
  for (int t = 0; t < WBAND; ++t) {
    const int j = left ? (i - 33 + t) : (i + t);
    const float pt = __shfl(p, t);
    if (j >= 0 && j < SEQ)
      o = fmaf(pt, Vb[(size_t)j * LDQ], o);
  }
  O[(size_t)b * SEQ * HID + (size_t)i * HID + h * 64 + d] = o;
}

// Highway elementwise: Y = g*Y + (1-g)*relu(nonlin); P=[M,1024]=(nonlin|gate)
__global__ __launch_bounds__(256)
void highway_ew(float* __restrict__ Y, const float* __restrict__ P, int total) {
  int idx = blockIdx.x * blockDim.x + threadIdx.x;  // over M*128 float4s
  if (idx >= total) return;
  int m = idx >> 7;
  int c4 = (idx & 127) << 2;
  float4 nl = *(const float4*)(P + (size_t)m * 1024 + c4);
  float4 gt = *(const float4*)(P + (size_t)m * 1024 + 512 + c4);
  float4 y = ((const float4*)Y)[idx];
  float g0 = 1.f / (1.f + __expf(-gt.x));
  float g1 = 1.f / (1.f + __expf(-gt.y));
  float g2 = 1.f / (1.f + __expf(-gt.z));
  float g3 = 1.f / (1.f + __expf(-gt.w));
  y.x = g0 * y.x + (1.f - g0) * fmaxf(nl.x, 0.f);
  y.y = g1 * y.y + (1.f - g1) * fmaxf(nl.y, 0.f);
  y.z = g2 * y.z + (1.f - g2) * fmaxf(nl.z, 0.f);
  y.w = g3 * y.w + (1.f - g3) * fmaxf(nl.w, 0.f);
  ((float4*)Y)[idx] = y;
}

// Optional residual add, then scatter into out[l,b,s,dir*512 + c].
__global__ __launch_bounds__(256)
void resid_store(float* __restrict__ Y, const float* __restrict__ X,
                 float* __restrict__ out, int addres, int total) {
  int idx = blockIdx.x * blockDim.x + threadIdx.x;  // over M*128 float4s
  if (idx >= total) return;
  float4 y = ((const float4*)Y)[idx];
  if (addres) {
    float4 x = ((const float4*)X)[idx];
    y.x += x.x; y.y += x.y; y.z += x.z; y.w += x.w;
  }
  ((float4*)Y)[idx] = y;
  int m = idx >> 7;
  int c4 = (idx & 127) << 2;
  *(float4*)(out + (size_t)m * 1024 + c4) = y;
}

extern "C" void kernel_launch(void* const* d_in, const int* in_sizes, int n_in,
                              void* d_out, int out_size, void* d_ws, size_t ws_size,
                              hipStream_t stream) {
  const float* x_in  = (const float*)d_in[0];
  // d_in[1] = masks (unused by forward)
  const float* qkv_w = (const float*)d_in[2];
  const float* qkv_b = (const float*)d_in[3];
  const float* rel   = (const float*)d_in[4];
  const float* hw_w  = (const float*)d_in[5];
  const float* hw_b  = (const float*)d_in[6];
  float* out = (float*)d_out;
  char* ws = (char*)d_ws;

  const size_t U = (size_t)MROWS * HID * sizeof(float);  // 8 MB unit
  float* Xf   = (float*)(ws + 0 * U);
  float* Yf   = (float*)(ws + 1 * U);
  float* Xb   = (float*)(ws + 2 * U);
  float* Yb   = (float*)(ws + 3 * U);
  float* QKV  = (float*)(ws + 4 * U);  // 3 units [M,1536]
  float* ATT  = (float*)(ws + 7 * U);  // 1 unit  [M,512]
  float* PROJ = (float*)(ws + 4 * U);  // aliases QKV (dead after attention): [M,1024]

  hipMemcpyAsync(Xf, x_in, U, hipMemcpyDeviceToDevice, stream);
  hipMemcpyAsync(Xb, x_in, U, hipMemcpyDeviceToDevice, stream);

  float* cur[2] = {Xf, Xb};
  float* alt[2] = {Yf, Yb};

  for (int l = 0; l < LYR; ++l) {
    for (int dir = 0; dir < 2; ++dir) {
      float* X = cur[dir];
      float* Y = alt[dir];
      const float* Wq = qkv_w + (size_t)(l * 2 + dir) * 4 * HID * HID;
      const float* bq = qkv_b + (size_t)(l * 2 + dir) * 4 * HID;

      // Fused QKV projection: W rows [q|k|v] are contiguous -> N=1536
      dim3 g1(1536 / BN, MROWS / BM);
      gemm_bt<<<g1, 256, 0, stream>>>(X, Wq, bq, QKV, MROWS, 1536, HID, 1536);

      band_attn<<<dim3(SEQ / 4, NH, BATCH), 256, 0, stream>>>(
          QKV, rel + (size_t)(l * 2 + dir) * NH * WBAND, ATT, dir == 0);

      dim3 g2(512 / BN, MROWS / BM);
      gemm_bt<<<g2, 256, 0, stream>>>(ATT, Wq + (size_t)3 * HID * HID,
                                      bq + 3 * HID, Y, MROWS, 512, HID, 512);

      for (int k2 = 0; k2 < 2; ++k2) {
        const float* Wh = hw_w + (size_t)((l * 2 + dir) * 2 + k2) * 1024 * HID;
        const float* bh = hw_b + (size_t)((l * 2 + dir) * 2 + k2) * 1024;
        dim3 g3(1024 / BN, MROWS / BM);
        gemm_bt<<<g3, 256, 0, stream>>>(Y, Wh, bh, PROJ, MROWS, 1024, HID, 1024);
        highway_ew<<<(MROWS * 128 + 255) / 256, 256, 0, stream>>>(Y, PROJ, MROWS * 128);
      }

      resid_store<<<(MROWS * 128 + 255) / 256, 256, 0, stream>>>(
          Y, X, out + (size_t)l * MROWS * 1024 + dir * 512, l > 0, MROWS * 128);

      cur[dir] = Y;
      alt[dir] = X;
    }
  }
}

// Round 3
// 885.624 us; speedup vs baseline: 1.6813x; 1.6813x over previous
//
#include <hip/hip_runtime.h>
#include <hip/hip_bf16.h>
#include <cstddef>

// Problem constants
#define LYR 2
#define NH 8
#define HID 512
#define SEQ 1024
#define BATCH 4
#define WBAND 34   // W+1 = 34 valid relative offsets
#define MROWS (BATCH*SEQ)   // 4096

typedef __attribute__((ext_vector_type(8))) short short8;
typedef __attribute__((ext_vector_type(4))) float f32x4;

// ---------------- MFMA GEMM (bf16x3 split precision) ----------------
// C[M,N] = A[M,K=512] @ W[N,K=512]^T + bias[N].
// Block: 256 thr = 4 waves (2x2), tile 128x128, each wave 64x64 (4x4 frags).
#define TM 128
#define TN 128
#define TK 32
#define LDT 40   // padded LDS row stride in bf16 (80B = 20 dwords -> 2-way only)

__device__ __forceinline__ ushort bf_hi(float x) {
  return (ushort)(__float_as_uint(x) >> 16);
}
__device__ __forceinline__ float bf_res(float x) {
  return x - __uint_as_float(__float_as_uint(x) & 0xffff0000u);
}
__device__ __forceinline__ void cvt4(float4 v, ushort4& h, ushort4& l) {
  h.x = bf_hi(v.x); h.y = bf_hi(v.y); h.z = bf_hi(v.z); h.w = bf_hi(v.w);
  l.x = bf_hi(bf_res(v.x)); l.y = bf_hi(bf_res(v.y));
  l.z = bf_hi(bf_res(v.z)); l.w = bf_hi(bf_res(v.w));
}

__global__ __launch_bounds__(256, 2)
void gemm_mfma_bt(const float* __restrict__ A, const float* __restrict__ W,
                  const float* __restrict__ bias, float* __restrict__ C,
                  int ldc) {
  __shared__ ushort Ahi[TM * LDT], Alo[TM * LDT];
  __shared__ ushort Bhi[TN * LDT], Blo[TN * LDT];

  const int tid = threadIdx.x;
  const int lane = tid & 63;
  const int wid = tid >> 6;
  const int wm = wid >> 1, wn = wid & 1;
  const int fr = lane & 15;       // frag row/col
  const int fq = lane >> 4;       // k-octet
  const int bm = blockIdx.y * TM;
  const int bn = blockIdx.x * TN;

  // staging: thread covers rows (tid>>3)+rep*32, float4 #(tid&7)
  const int arow = tid >> 3;
  const int akq = tid & 7;
  const float* Ag = A + (size_t)(bm + arow) * 512 + akq * 4;
  const float* Wg = W + (size_t)(bn + arow) * 512 + akq * 4;

  float4 ra[4], rb[4];
#define LOADT(k0)                                                      \
  _Pragma("unroll") for (int rep = 0; rep < 4; ++rep) {                \
    ra[rep] = *(const float4*)(Ag + (size_t)rep * 32 * 512 + (k0));    \
    rb[rep] = *(const float4*)(Wg + (size_t)rep * 32 * 512 + (k0));    \
  }

  f32x4 acc[4][4] = {};

  LOADT(0);
  for (int k0 = 0; k0 < 512; k0 += TK) {
    __syncthreads();   // previous tile's reads complete
#pragma unroll
    for (int rep = 0; rep < 4; ++rep) {
      const int off = (arow + rep * 32) * LDT + akq * 4;
      ushort4 h, l;
      cvt4(ra[rep], h, l);
      *(ushort4*)&Ahi[off] = h; *(ushort4*)&Alo[off] = l;
      cvt4(rb[rep], h, l);
      *(ushort4*)&Bhi[off] = h; *(ushort4*)&Blo[off] = l;
    }
    __syncthreads();
    if (k0 + TK < 512) { LOADT(k0 + TK); }

    short8 ah[4], al[4], bh[4], bl[4];
    const int abase = (wm * 64 + fr) * LDT + fq * 8;
    const int bbase = (wn * 64 + fr) * LDT + fq * 8;
#pragma unroll
    for (int m = 0; m < 4; ++m) {
      ah[m] = *(const short8*)&Ahi[abase + m * 16 * LDT];
      al[m] = *(const short8*)&Alo[abase + m * 16 * LDT];
    }
#pragma unroll
    for (int n = 0; n < 4; ++n) {
      bh[n] = *(const short8*)&Bhi[bbase + n * 16 * LDT];
      bl[n] = *(const short8*)&Blo[bbase + n * 16 * LDT];
    }
#pragma unroll
    for (int m = 0; m < 4; ++m)
#pragma unroll
      for (int n = 0; n < 4; ++n) {
        acc[m][n] = __builtin_amdgcn_mfma_f32_16x16x32_bf16(ah[m], bh[n], acc[m][n], 0, 0, 0);
        acc[m][n] = __builtin_amdgcn_mfma_f32_16x16x32_bf16(ah[m], bl[n], acc[m][n], 0, 0, 0);
        acc[m][n] = __builtin_amdgcn_mfma_f32_16x16x32_bf16(al[m], bh[n], acc[m][n], 0, 0, 0);
      }
  }

  // C/D layout: col = lane&15, row = (lane>>4)*4 + reg
  const int cn0 = bn + wn * 64 + fr;
#pragma unroll
  for (int n = 0; n < 4; ++n) {
    const float bv = bias[cn0 + n * 16];
#pragma unroll
    for (int m = 0; m < 4; ++m) {
      const int row0 = bm + wm * 64 + m * 16 + fq * 4;
#pragma unroll
      for (int r = 0; r < 4; ++r)
        C[(size_t)(row0 + r) * ldc + cn0 + n * 16] = acc[m][n][r] + bv;
    }
  }
#undef LOADT
}

// ---------------- Banded attention ----------------
// QKV: [B*S, 1536] rows = [q|k|v]. One wave per (b,h,i). O: [B*S, 512].
__global__ __launch_bounds__(256)
void band_attn(const float* __restrict__ QKV, const float* __restrict__ rel,
               float* __restrict__ O, int left) {
  const int LDQ = 3 * HID;
  const int wave = threadIdx.x >> 6;
  const int lane = threadIdx.x & 63;
  const int i = (blockIdx.x << 2) + wave;
  const int h = blockIdx.y;
  const int b = blockIdx.z;
  const size_t rowbase = (size_t)b * SEQ * LDQ + h * 64;
  const float* Qr = QKV + rowbase + (size_t)i * LDQ;

  float score = -1e30f;
  {
    const int t = lane;
    const int j = left ? (i - 33 + t) : (i + t);
    if (t < WBAND && j >= 0 && j < SEQ) {
      const float4* q4 = (const float4*)Qr;
      const float4* k4 = (const float4*)(QKV + rowbase + 512 + (size_t)j * LDQ);
      float s = 0.f;
#pragma unroll
      for (int dd = 0; dd < 16; ++dd) {
        float4 q = q4[dd], k = k4[dd];
        s = fmaf(q.x, k.x, fmaf(q.y, k.y, fmaf(q.z, k.z, fmaf(q.w, k.w, s))));
      }
      score = s * 0.125f + rel[h * WBAND + t];
    }
  }
  float m = score;
#pragma unroll
  for (int off = 32; off; off >>= 1) m = fmaxf(m, __shfl_xor(m, off));
  float p = __expf(score - m);
  float sum = p;
#pragma unroll
  for (int off = 32; off; off >>= 1) sum += __shfl_xor(sum, off);
  p /= sum;
  float o = 0.f;
  const int d = lane;
  const float* Vb = QKV + rowbase + 1024 + d;
  for (int t = 0; t < WBAND; ++t) {
    const int j = left ? (i - 33 + t) : (i + t);
    const float pt = __shfl(p, t);
    if (j >= 0 && j < SEQ)
      o = fmaf(pt, Vb[(size_t)j * LDQ], o);
  }
  O[(size_t)b * SEQ * HID + (size_t)i * HID + h * 64 + d] = o;
}

// ---------------- Highway elementwise ----------------
__global__ __launch_bounds__(256)
void highway_ew(float* __restrict__ Y, const float* __restrict__ P, int total) {
  int idx = blockIdx.x * blockDim.x + threadIdx.x;
  if (idx >= total) return;
  int m = idx >> 7;
  int c4 = (idx & 127) << 2;
  float4 nl = *(const float4*)(P + (size_t)m * 1024 + c4);
  float4 gt = *(const float4*)(P + (size_t)m * 1024 + 512 + c4);
  float4 y = ((const float4*)Y)[idx];
  float g0 = 1.f / (1.f + __expf(-gt.x));
  float g1 = 1.f / (1.f + __expf(-gt.y));
  float g2 = 1.f / (1.f + __expf(-gt.z));
  float g3 = 1.f / (1.f + __expf(-gt.w));
  y.x = g0 * y.x + (1.f - g0) * fmaxf(nl.x, 0.f);
  y.y = g1 * y.y + (1.f - g1) * fmaxf(nl.y, 0.f);
  y.z = g2 * y.z + (1.f - g2) * fmaxf(nl.z, 0.f);
  y.w = g3 * y.w + (1.f - g3) * fmaxf(nl.w, 0.f);
  ((float4*)Y)[idx] = y;
}

// ---------------- Residual + store ----------------
__global__ __launch_bounds__(256)
void resid_store(float* __restrict__ Y, const float* __restrict__ X,
                 float* __restrict__ out, int addres, int total) {
  int idx = blockIdx.x * blockDim.x + threadIdx.x;
  if (idx >= total) return;
  float4 y = ((const float4*)Y)[idx];
  if (addres) {
    float4 x = ((const float4*)X)[idx];
    y.x += x.x; y.y += x.y; y.z += x.z; y.w += x.w;
  }
  ((float4*)Y)[idx] = y;
  int m = idx >> 7;
  int c4 = (idx & 127) << 2;
  *(float4*)(out + (size_t)m * 1024 + c4) = y;
}

extern "C" void kernel_launch(void* const* d_in, const int* in_sizes, int n_in,
                              void* d_out, int out_size, void* d_ws, size_t ws_size,
                              hipStream_t stream) {
  const float* x_in  = (const float*)d_in[0];
  const float* qkv_w = (const float*)d_in[2];
  const float* qkv_b = (const float*)d_in[3];
  const float* rel   = (const float*)d_in[4];
  const float* hw_w  = (const float*)d_in[5];
  const float* hw_b  = (const float*)d_in[6];
  float* out = (float*)d_out;
  char* ws = (char*)d_ws;

  const size_t U = (size_t)MROWS * HID * sizeof(float);  // 8 MB unit
  float* Xf   = (float*)(ws + 0 * U);
  float* Yf   = (float*)(ws + 1 * U);
  float* Xb   = (float*)(ws + 2 * U);
  float* Yb   = (float*)(ws + 3 * U);
  float* QKV  = (float*)(ws + 4 * U);  // 3 units [M,1536]
  float* ATT  = (float*)(ws + 7 * U);  // 1 unit  [M,512]
  float* PROJ = (float*)(ws + 4 * U);  // aliases QKV (dead after attention)

  hipMemcpyAsync(Xf, x_in, U, hipMemcpyDeviceToDevice, stream);
  hipMemcpyAsync(Xb, x_in, U, hipMemcpyDeviceToDevice, stream);

  float* cur[2] = {Xf, Xb};
  float* alt[2] = {Yf, Yb};

  for (int l = 0; l < LYR; ++l) {
    for (int dir = 0; dir < 2; ++dir) {
      float* X = cur[dir];
      float* Y = alt[dir];
      const float* Wq = qkv_w + (size_t)(l * 2 + dir) * 4 * HID * HID;
      const float* bq = qkv_b + (size_t)(l * 2 + dir) * 4 * HID;

      gemm_mfma_bt<<<dim3(1536 / TN, MROWS / TM), 256, 0, stream>>>(
          X, Wq, bq, QKV, 1536);

      band_attn<<<dim3(SEQ / 4, NH, BATCH), 256, 0, stream>>>(
          QKV, rel + (size_t)(l * 2 + dir) * NH * WBAND, ATT, dir == 0);

      gemm_mfma_bt<<<dim3(512 / TN, MROWS / TM), 256, 0, stream>>>(
          ATT, Wq + (size_t)3 * HID * HID, bq + 3 * HID, Y, 512);

      for (int k2 = 0; k2 < 2; ++k2) {
        const float* Wh = hw_w + (size_t)((l * 2 + dir) * 2 + k2) * 1024 * HID;
        const float* bh = hw_b + (size_t)((l * 2 + dir) * 2 + k2) * 1024;
        gemm_mfma_bt<<<dim3(1024 / TN, MROWS / TM), 256, 0, stream>>>(
            Y, Wh, bh, PROJ, 1024);
        highway_ew<<<(MROWS * 128 + 255) / 256, 256, 0, stream>>>(Y, PROJ, MROWS * 128);
      }

      resid_store<<<(MROWS * 128 + 255) / 256, 256, 0, stream>>>(
          Y, X, out + (size_t)l * MROWS * 1024 + dir * 512, l > 0, MROWS * 128);

      cur[dir] = Y;
      alt[dir] = X;
    }
  }
}

// Round 5
// 780.293 us; speedup vs baseline: 1.9082x; 1.1350x over previous
//
#include <hip/hip_runtime.h>
#include <hip/hip_bf16.h>
#include <cstddef>

#define LYR 2
#define NH 8
#define HID 512
#define SEQ 1024
#define BATCH 4
#define WBAND 34
#define MROWS (BATCH*SEQ)   // 4096

typedef __attribute__((ext_vector_type(8))) short short8;
typedef __attribute__((ext_vector_type(4))) float f32x4;

__device__ __forceinline__ ushort bf_hi(float x) {
  return (ushort)(__float_as_uint(x) >> 16);
}
__device__ __forceinline__ float bf_res(float x) {
  return x - __uint_as_float(__float_as_uint(x) & 0xffff0000u);
}
__device__ __forceinline__ float rec1(ushort h, ushort l) {
  return __uint_as_float((uint)h << 16) + __uint_as_float((uint)l << 16);
}
__device__ __forceinline__ void cvt4(float4 v, ushort4& h, ushort4& l) {
  h.x = bf_hi(v.x); h.y = bf_hi(v.y); h.z = bf_hi(v.z); h.w = bf_hi(v.w);
  l.x = bf_hi(bf_res(v.x)); l.y = bf_hi(bf_res(v.y));
  l.z = bf_hi(bf_res(v.z)); l.w = bf_hi(bf_res(v.w));
}

#define GLOAD16(gp, lp)                                                        \
  __builtin_amdgcn_global_load_lds(                                            \
      (const __attribute__((address_space(1))) void*)(gp),                     \
      (__attribute__((address_space(3))) void*)(lp), 16, 0, 0)

// ------------- split-precision bf16x3 GEMM, m97-style staging -------------
// C[4096,N] = rec(A) @ rec(W)^T + bias. A,W given as hi/lo bf16 planes, K=512.
// Writes either Cf (fp32) or Chi/Clo planes.
__global__ __launch_bounds__(256, 2)
void gemm_hl(const ushort* __restrict__ Ahi, const ushort* __restrict__ Alo,
             const ushort* __restrict__ Whi, const ushort* __restrict__ Wlo,
             const float* __restrict__ bias, float* __restrict__ Cf,
             ushort* __restrict__ Chi, ushort* __restrict__ Clo, int N) {
  __shared__ ushort lds[4 * 4096];  // planes: Ahi Alo Bhi Blo, each [128][32]
  const int tid = threadIdx.x;
  const int lane = tid & 63, wid = tid >> 6;
  const int wm = wid >> 1, wn = wid & 1;
  const int fr = lane & 15, fq = lane >> 4;
  const int bm = blockIdx.y * 128, bn = blockIdx.x * 128;

  f32x4 acc[4][4] = {};

  for (int k0 = 0; k0 < 512; k0 += 32) {
    __syncthreads();
#pragma unroll
    for (int i = 0; i < 2; ++i) {
      const int c = tid + 256 * i;
      const int row = c >> 2, col = (c & 3) * 8;
      const size_t ga = (size_t)(bm + row) * 512 + k0 + col;
      const size_t gb = (size_t)(bn + row) * 512 + k0 + col;
      GLOAD16(Ahi + ga, &lds[0 * 4096 + c * 8]);
      GLOAD16(Alo + ga, &lds[1 * 4096 + c * 8]);
      GLOAD16(Whi + gb, &lds[2 * 4096 + c * 8]);
      GLOAD16(Wlo + gb, &lds[3 * 4096 + c * 8]);
    }
    __syncthreads();  // compiler drains vmcnt before barrier

    short8 ah[4], al[4], bh[4], bl[4];
#pragma unroll
    for (int m = 0; m < 4; ++m) {
      const int ro = (wm * 64 + m * 16 + fr) * 32 + fq * 8;
      ah[m] = *(const short8*)&lds[0 * 4096 + ro];
      al[m] = *(const short8*)&lds[1 * 4096 + ro];
    }
#pragma unroll
    for (int n = 0; n < 4; ++n) {
      const int ro = (wn * 64 + n * 16 + fr) * 32 + fq * 8;
      bh[n] = *(const short8*)&lds[2 * 4096 + ro];
      bl[n] = *(const short8*)&lds[3 * 4096 + ro];
    }
#pragma unroll
    for (int m = 0; m < 4; ++m)
#pragma unroll
      for (int n = 0; n < 4; ++n) {
        acc[m][n] = __builtin_amdgcn_mfma_f32_16x16x32_bf16(ah[m], bh[n], acc[m][n], 0, 0, 0);
        acc[m][n] = __builtin_amdgcn_mfma_f32_16x16x32_bf16(ah[m], bl[n], acc[m][n], 0, 0, 0);
        acc[m][n] = __builtin_amdgcn_mfma_f32_16x16x32_bf16(al[m], bh[n], acc[m][n], 0, 0, 0);
      }
  }

  // C/D: col = lane&15, row = (lane>>4)*4 + reg   [verified layout]
  const int cn0 = bn + wn * 64 + fr;
#pragma unroll
  for (int n = 0; n < 4; ++n) {
    const int col = cn0 + n * 16;
    const float bv = bias[col];
#pragma unroll
    for (int m = 0; m < 4; ++m) {
      const int row0 = bm + wm * 64 + m * 16 + fq * 4;
#pragma unroll
      for (int r = 0; r < 4; ++r) {
        const float v = acc[m][n][r] + bv;
        const size_t o = (size_t)(row0 + r) * N + col;
        if (Cf) {
          Cf[o] = v;
        } else {
          Chi[o] = bf_hi(v);
          Clo[o] = bf_hi(bf_res(v));
        }
      }
    }
  }
}

// ------------- banded attention with LDS-staged K/V tiles -------------
// QKV fp32 [4096][1536] rows = q|k|v. Block = (64 queries, head, batch).
// Output: hi/lo bf16 planes [4096][512].
#define KSTR 66
__global__ __launch_bounds__(256)
void band_attn2(const float* __restrict__ QKV, const float* __restrict__ rel,
                ushort* __restrict__ Oh, ushort* __restrict__ Ol, int left) {
  __shared__ float Kt[97 * KSTR];  // stride 66: float2 reads 2-way (free)
  __shared__ float Vt[97 * 64];    // lane=d reads conflict-free at stride 64
  const int tid = threadIdx.x, lane = tid & 63, w = tid >> 6;
  const int i0 = blockIdx.x * 64, h = blockIdx.y, b = blockIdx.z;
  const int j0 = left ? i0 - 33 : i0;
  const size_t base = (size_t)b * SEQ * 1536 + h * 64;

  // stage K,V rows j0..j0+96 (zero-fill OOB so p=0 * V never hits NaN)
  for (int s = 0; s < 13; ++s) {
    const int r = s * 8 + (tid >> 5);
    const int c = (tid & 31) * 2;
    if (r < 97) {
      const int j = j0 + r;
      float2 kv = make_float2(0.f, 0.f), vv = make_float2(0.f, 0.f);
      if (j >= 0 && j < SEQ) {
        kv = *(const float2*)(QKV + base + (size_t)j * 1536 + 512 + c);
        vv = *(const float2*)(QKV + base + (size_t)j * 1536 + 1024 + c);
      }
      Kt[r * KSTR + c] = kv.x; Kt[r * KSTR + c + 1] = kv.y;
      Vt[r * 64 + c] = vv.x;   Vt[r * 64 + c + 1] = vv.y;
    }
  }
  __syncthreads();

  const int t = lane;
  const float relb = (t < WBAND) ? rel[h * WBAND + t] : 0.f;

  for (int qq = 0; qq < 16; ++qq) {
    const int qi = w * 16 + qq;
    const int i = i0 + qi;
    const int j = left ? (i - 33 + t) : (i + t);
    float score = -1e30f;
    if (t < WBAND && j >= 0 && j < SEQ) {
      const float2* q2 = (const float2*)(QKV + base + (size_t)i * 1536);
      const float* kr = &Kt[(qi + t) * KSTR];
      float s = 0.f;
#pragma unroll
      for (int c = 0; c < 32; ++c) {
        const float2 q = q2[c];                      // broadcast (L1)
        const float2 k = *(const float2*)&kr[2 * c]; // 2-way bank: free
        s = fmaf(q.x, k.x, fmaf(q.y, k.y, s));
      }
      score = s * 0.125f + relb;
    }
    float m = score;
#pragma unroll
    for (int off = 32; off; off >>= 1) m = fmaxf(m, __shfl_xor(m, off));
    float p = __expf(score - m);
    float sum = p;
#pragma unroll
    for (int off = 32; off; off >>= 1) sum += __shfl_xor(sum, off);
    p /= sum;

    float o = 0.f;
    const float* vcol = &Vt[qi * 64 + lane];
#pragma unroll
    for (int tt = 0; tt < WBAND; ++tt)
      o = fmaf(__shfl(p, tt), vcol[tt * 64], o);

    const size_t oidx = ((size_t)b * SEQ + i) * 512 + h * 64 + lane;
    Oh[oidx] = bf_hi(o);
    Ol[oidx] = bf_hi(bf_res(o));
  }
}

// ------------- highway elementwise on hi/lo activations -------------
__global__ __launch_bounds__(256)
void highway_hl(ushort* __restrict__ YH, ushort* __restrict__ YL,
                const float* __restrict__ P) {
  const int idx = blockIdx.x * 256 + threadIdx.x;  // 524288 float4-groups
  const int m = idx >> 7, c4 = (idx & 127) << 2;
  const float* pr = P + (size_t)m * 1024 + c4;
  const float4 nl = *(const float4*)pr;
  const float4 gt = *(const float4*)(pr + 512);
  const ushort4 yh = *(const ushort4*)(YH + (size_t)idx * 4);
  const ushort4 yl = *(const ushort4*)(YL + (size_t)idx * 4);
  float y[4] = {rec1(yh.x, yl.x), rec1(yh.y, yl.y), rec1(yh.z, yl.z), rec1(yh.w, yl.w)};
  const float n[4] = {nl.x, nl.y, nl.z, nl.w};
  const float g[4] = {gt.x, gt.y, gt.z, gt.w};
#pragma unroll
  for (int k = 0; k < 4; ++k) {
    const float gg = 1.f / (1.f + __expf(-g[k]));
    y[k] = gg * y[k] + (1.f - gg) * fmaxf(n[k], 0.f);
  }
  ushort4 oh, ol;
  cvt4(make_float4(y[0], y[1], y[2], y[3]), oh, ol);
  *(ushort4*)(YH + (size_t)idx * 4) = oh;
  *(ushort4*)(YL + (size_t)idx * 4) = ol;
}

// ------------- residual + output store -------------
__global__ __launch_bounds__(256)
void resid_hl(ushort* __restrict__ YH, ushort* __restrict__ YL,
              const ushort* __restrict__ XH, const ushort* __restrict__ XL,
              float* __restrict__ outp, int addres) {
  const int idx = blockIdx.x * 256 + threadIdx.x;
  const int m = idx >> 7, c4 = (idx & 127) << 2;
  const ushort4 yh = *(const ushort4*)(YH + (size_t)idx * 4);
  const ushort4 yl = *(const ushort4*)(YL + (size_t)idx * 4);
  float y[4] = {rec1(yh.x, yl.x), rec1(yh.y, yl.y), rec1(yh.z, yl.z), rec1(yh.w, yl.w)};
  if (addres) {
    const ushort4 xh = *(const ushort4*)(XH + (size_t)idx * 4);
    const ushort4 xl = *(const ushort4*)(XL + (size_t)idx * 4);
    y[0] += rec1(xh.x, xl.x); y[1] += rec1(xh.y, xl.y);
    y[2] += rec1(xh.z, xl.z); y[3] += rec1(xh.w, xl.w);
    ushort4 oh, ol;
    cvt4(make_float4(y[0], y[1], y[2], y[3]), oh, ol);
    *(ushort4*)(YH + (size_t)idx * 4) = oh;
    *(ushort4*)(YL + (size_t)idx * 4) = ol;
  }
  *(float4*)(outp + (size_t)m * 1024 + c4) = make_float4(y[0], y[1], y[2], y[3]);
}

// ------------- fp32 -> hi/lo split converters -------------
__global__ __launch_bounds__(256)
void convert_pair(const float* __restrict__ src, ushort* __restrict__ h,
                  ushort* __restrict__ l, int n4) {
  const int idx = blockIdx.x * 256 + threadIdx.x;
  if (idx >= n4) return;
  const float4 v = ((const float4*)src)[idx];
  ushort4 hh, ll;
  cvt4(v, hh, ll);
  ((ushort4*)h)[idx] = hh;
  ((ushort4*)l)[idx] = ll;
}

// per-pass weights: [qkv 1048576 floats][hw 1048576 floats] -> one buffer
__global__ __launch_bounds__(256)
void convert_w(const float* __restrict__ qsrc, const float* __restrict__ hsrc,
               ushort* __restrict__ h, ushort* __restrict__ l) {
  const int idx = blockIdx.x * 256 + threadIdx.x;  // 0..524287
  const float4 v = (idx < 262144) ? ((const float4*)qsrc)[idx]
                                  : ((const float4*)hsrc)[idx - 262144];
  ushort4 hh, ll;
  cvt4(v, hh, ll);
  ((ushort4*)h)[idx] = hh;
  ((ushort4*)l)[idx] = ll;
}

extern "C" void kernel_launch(void* const* d_in, const int* in_sizes, int n_in,
                              void* d_out, int out_size, void* d_ws, size_t ws_size,
                              hipStream_t stream) {
  const float* x_in  = (const float*)d_in[0];
  const float* qkv_w = (const float*)d_in[2];
  const float* qkv_b = (const float*)d_in[3];
  const float* rel   = (const float*)d_in[4];
  const float* hw_w  = (const float*)d_in[5];
  const float* hw_b  = (const float*)d_in[6];
  float* out = (float*)d_out;
  char* ws = (char*)d_ws;

  const size_t ACT = (size_t)MROWS * HID * 2;       // 4 MB (one bf16 plane)
  float* QKVbuf = (float*)ws;                        // 25.2 MB fp32
  float* P      = (float*)ws;                        // aliases (16.8 MB, after attn)
  char* q = ws + (size_t)MROWS * 1536 * 4;
  ushort* ATTH = (ushort*)q;            q += ACT;
  ushort* ATTL = (ushort*)q;            q += ACT;
  ushort* actH[4], *actL[4];
  for (int i = 0; i < 4; ++i) { actH[i] = (ushort*)q; q += ACT; actL[i] = (ushort*)q; q += ACT; }
  ushort* WPH = (ushort*)q;             q += (size_t)2097152 * 2;
  ushort* WPL = (ushort*)q;

  // initial split of x (shared by both dirs at l=0)
  convert_pair<<<2048, 256, 0, stream>>>(x_in, actH[0], actL[0], MROWS * HID / 4);

  int cur[2] = {0, 0};
  const int alt_idx[2][2] = {{1, 2}, {0, 3}};

  for (int l = 0; l < LYR; ++l) {
    for (int dir = 0; dir < 2; ++dir) {
      const int ci = cur[dir];
      const int ai = alt_idx[l][dir];
      const float* bq = qkv_b + (size_t)(l * 2 + dir) * 4 * HID;
      const float* bh = hw_b + (size_t)(l * 2 + dir) * 2 * 1024;

      convert_w<<<2048, 256, 0, stream>>>(
          qkv_w + (size_t)(l * 2 + dir) * 4 * HID * HID,
          hw_w + (size_t)(l * 2 + dir) * 2 * 1024 * HID, WPH, WPL);

      // QKV projection (W rows 0..1535 = q|k|v)
      gemm_hl<<<dim3(12, 32), 256, 0, stream>>>(
          actH[ci], actL[ci], WPH, WPL, bq, QKVbuf, nullptr, nullptr, 1536);

      band_attn2<<<dim3(16, NH, BATCH), 256, 0, stream>>>(
          QKVbuf, rel + (size_t)(l * 2 + dir) * NH * WBAND, ATTH, ATTL, dir == 0);

      // out-projection (W rows 1536..2047), writes hi/lo
      gemm_hl<<<dim3(4, 32), 256, 0, stream>>>(
          ATTH, ATTL, WPH + 786432, WPL + 786432, bq + 3 * HID,
          nullptr, actH[ai], actL[ai], 512);

      // highway x2
      gemm_hl<<<dim3(8, 32), 256, 0, stream>>>(
          actH[ai], actL[ai], WPH + 1048576, WPL + 1048576, bh,
          P, nullptr, nullptr, 1024);
      highway_hl<<<2048, 256, 0, stream>>>(actH[ai], actL[ai], P);

      gemm_hl<<<dim3(8, 32), 256, 0, stream>>>(
          actH[ai], actL[ai], WPH + 1572864, WPL + 1572864, bh + 1024,
          P, nullptr, nullptr, 1024);
      highway_hl<<<2048, 256, 0, stream>>>(actH[ai], actL[ai], P);

      resid_hl<<<2048, 256, 0, stream>>>(
          actH[ai], actL[ai], actH[ci], actL[ci],
          out + (size_t)l * MROWS * 1024 + dir * 512, l > 0);

      cur[dir] = ai;
    }
  }
}